// Round 1
// baseline (1339.484 us; speedup 1.0000x reference)
//
#include <hip/hip_runtime.h>
#include <stdint.h>

typedef unsigned int u32;
typedef unsigned long long u64;

#define DIMS 512
#define NBINS 4096
#define CAPA 128
#define CAPB 8192
#define SORTN 4096

// Monotonic float->uint key: descending float order == descending key order.
__device__ __forceinline__ u32 f2key(float f) {
  u32 u = __float_as_uint(f);
  return (u & 0x80000000u) ? ~u : (u | 0x80000000u);
}
__device__ __forceinline__ float key2f(u32 k) {
  u32 u = (k & 0x80000000u) ? (k & 0x7fffffffu) : ~k;
  return __uint_as_float(u);
}

// Zero the histogram + the two compact counters (ws is poisoned 0xAA).
__global__ __launch_bounds__(256) void init_kernel(u32* __restrict__ ghist,
                                                   u32* __restrict__ cnts) {
  int i = blockIdx.x * 256 + threadIdx.x;
  for (int j = i; j < NBINS; j += gridDim.x * 256) ghist[j] = 0;
  if (i < 2) cnts[i] = 0;
}

// One wave per row: coalesced 2x float4 per lane (2KB/row), fp64 accumulate,
// shuffle reduce, lane0 writes sim + LDS-hist of top 12 key bits.
__global__ __launch_bounds__(256) void sims_kernel(
    const float* __restrict__ q, const float* __restrict__ db,
    float* __restrict__ sims, u32* __restrict__ ghist, int nrows) {
  __shared__ __align__(16) float sq[DIMS];
  __shared__ u32 hist[NBINS];
  __shared__ float warp_ss[4];
  __shared__ float s_qn;

  for (int i = threadIdx.x; i < NBINS; i += 256) hist[i] = 0;

  // Load query into LDS + compute ||q|| (block of 256, D=512).
  float v0 = q[threadIdx.x];
  float v1 = q[threadIdx.x + 256];
  sq[threadIdx.x] = v0;
  sq[threadIdx.x + 256] = v1;
  float ss = v0 * v0 + v1 * v1;
#pragma unroll
  for (int o = 32; o > 0; o >>= 1) ss += __shfl_down(ss, o);
  if ((threadIdx.x & 63) == 0) warp_ss[threadIdx.x >> 6] = ss;
  __syncthreads();
  if (threadIdx.x == 0)
    s_qn = fmaxf(sqrtf(warp_ss[0] + warp_ss[1] + warp_ss[2] + warp_ss[3]), 1e-8f);
  __syncthreads();
  float qn = s_qn;

  int lane = threadIdx.x & 63;
  int wave = blockIdx.x * 4 + (threadIdx.x >> 6);
  int nw = gridDim.x * 4;

  // Hoist this lane's 8 query elements to registers.
  float4 qva = *((const float4*)sq + lane);
  float4 qvb = *((const float4*)sq + 64 + lane);

  for (int r = wave; r < nrows; r += nw) {
    const float4* rp = (const float4*)(db + (size_t)r * DIMS);
    float4 a = rp[lane];       // cols 4*lane .. 4*lane+3      (bytes 0..1023)
    float4 b = rp[lane + 64];  // cols 256+4*lane ..           (bytes 1024..2047)

    double dot = (double)a.x * qva.x + (double)a.y * qva.y +
                 (double)a.z * qva.z + (double)a.w * qva.w +
                 (double)b.x * qvb.x + (double)b.y * qvb.y +
                 (double)b.z * qvb.z + (double)b.w * qvb.w;
    double n2 = (double)a.x * a.x + (double)a.y * a.y + (double)a.z * a.z +
                (double)a.w * a.w + (double)b.x * b.x + (double)b.y * b.y +
                (double)b.z * b.z + (double)b.w * b.w;
#pragma unroll
    for (int o = 32; o > 0; o >>= 1) {
      dot += __shfl_down(dot, o);
      n2 += __shfl_down(n2, o);
    }
    if (lane == 0) {
      double s = dot / (fmax(sqrt(n2), 1e-8) * (double)qn);
      float sf = (float)s;
      sims[r] = sf;
      atomicAdd(&hist[f2key(sf) >> 20], 1u);
    }
  }
  __syncthreads();
  for (int i = threadIdx.x; i < NBINS; i += 256) {
    u32 c = hist[i];
    if (c) atomicAdd(&ghist[i], c);
  }
}

// Single block: suffix-count from the top bin to find threshold bin T with
// count(bins > T) < K <= count(bins >= T).
__global__ __launch_bounds__(256) void scan_kernel(const u32* __restrict__ ghist,
                                                   u32* __restrict__ hdr, int K) {
  __shared__ u32 seg[256];
  int t = threadIdx.x;
  int base = NBINS - 1 - 16 * t;  // this thread's 16 bins, descending
  u32 sum = 0;
#pragma unroll
  for (int m = 0; m < 16; m++) sum += ghist[base - m];
  seg[t] = sum;
  __syncthreads();
  for (int o = 1; o < 256; o <<= 1) {
    u32 v = (t >= o) ? seg[t - o] : 0;
    __syncthreads();
    seg[t] += v;
    __syncthreads();
  }
  u32 incl = seg[t];
  u32 excl = incl - sum;
  if (excl < (u32)K && (u32)K <= incl) {
    u32 c = excl;
    u32 T = 0;
    for (int m = 0; m < 16; m++) {
      u32 h = ghist[base - m];
      if (c + h >= (u32)K) { T = (u32)(base - m); break; }
      c += h;
    }
    hdr[0] = T;
    hdr[1] = c;  // count strictly above T (< K)
  }
}

// Compact: bin>T -> candA (guaranteed top), bin==T -> candB.
__global__ __launch_bounds__(256) void compact_kernel(
    const float* __restrict__ sims, const u32* __restrict__ hdr,
    u32* __restrict__ cnts, u64* __restrict__ candA, u64* __restrict__ candB,
    int n) {
  u32 T = hdr[0];
  int stride = gridDim.x * 256;
  for (int i = blockIdx.x * 256 + threadIdx.x; i < n; i += stride) {
    u32 key = f2key(sims[i]);
    u32 bin = key >> 20;
    if (bin >= T) {
      // ~idx as secondary key: descending u64 sort => ties give smaller idx first.
      u64 comp = ((u64)key << 32) | (u32)(~(u32)i);
      if (bin > T) {
        u32 p = atomicAdd(&cnts[0], 1u);
        if (p < CAPA) candA[p] = comp;
      } else {
        u32 p = atomicAdd(&cnts[1], 1u);
        if (p < CAPB) candB[p] = comp;
      }
    }
  }
}

// Single block: bitonic sort (descending) of <=SORTN candidates, write outputs.
__global__ __launch_bounds__(1024) void final_kernel(
    const u64* __restrict__ candA, const u64* __restrict__ candB,
    const u32* __restrict__ cnts, float* __restrict__ out, int K) {
  __shared__ u64 s[SORTN];
  u32 na = min(cnts[0], (u32)CAPA);
  u32 nb = min(cnts[1], (u32)CAPB);
  nb = min(nb, (u32)(SORTN - na));
  for (u32 i = threadIdx.x; i < SORTN; i += 1024) {
    u64 v = 0;  // key 0 sorts below every real key
    if (i < na) v = candA[i];
    else if (i < na + nb) v = candB[i - na];
    s[i] = v;
  }
  __syncthreads();
  for (u32 k = 2; k <= SORTN; k <<= 1) {
    for (u32 j = k >> 1; j > 0; j >>= 1) {
      for (u32 i = threadIdx.x; i < SORTN; i += 1024) {
        u32 ixj = i ^ j;
        if (ixj > i) {
          u64 a = s[i], b = s[ixj];
          bool sw = ((i & k) == 0) ? (a < b) : (a > b);
          if (sw) { s[i] = b; s[ixj] = a; }
        }
      }
      __syncthreads();
    }
  }
  if (threadIdx.x < (u32)K) {
    u64 v = s[threadIdx.x];
    out[threadIdx.x] = key2f((u32)(v >> 32));          // value
    out[K + threadIdx.x] = (float)(~(u32)v);           // index (exact in fp32)
  }
}

extern "C" void kernel_launch(void* const* d_in, const int* in_sizes, int n_in,
                              void* d_out, int out_size, void* d_ws,
                              size_t ws_size, hipStream_t stream) {
  const float* q = (const float*)d_in[0];
  const float* db = (const float*)d_in[1];
  float* out = (float*)d_out;

  int n = in_sizes[1] / DIMS;  // 500000
  int K = out_size / 2;        // 100 (values + indices concatenated)

  // Workspace layout (bytes): needs ~2.1 MB.
  char* ws = (char*)d_ws;
  float* sims = (float*)(ws + 0);             // 500000 * 4 = 2,000,000
  u32* ghist = (u32*)(ws + 2000000);          // 4096 * 4  = 16,384
  u32* hdr   = (u32*)(ws + 2016384);          // 2 * 4
  u32* cnts  = (u32*)(ws + 2016392);          // 2 * 4
  u64* candA = (u64*)(ws + 2016400);          // 128 * 8
  u64* candB = (u64*)(ws + 2017424);          // 8192 * 8

  hipLaunchKernelGGL(init_kernel, dim3(16), dim3(256), 0, stream, ghist, cnts);
  hipLaunchKernelGGL(sims_kernel, dim3(2048), dim3(256), 0, stream, q, db, sims,
                     ghist, n);
  hipLaunchKernelGGL(scan_kernel, dim3(1), dim3(256), 0, stream, ghist, hdr, K);
  hipLaunchKernelGGL(compact_kernel, dim3(256), dim3(256), 0, stream, sims, hdr,
                     cnts, candA, candB, n);
  hipLaunchKernelGGL(final_kernel, dim3(1), dim3(1024), 0, stream, candA, candB,
                     cnts, out, K);
}